// Round 10
// baseline (110.511 us; speedup 1.0000x reference)
//
#include <hip/hip_runtime.h>

#define T_TOTAL 200000
#define NL 49
#define NP 50
#define NB 20
#define TB 32                       // timesteps per block; 200000 % 32 == 0
#define THREADS 256                 // 4 waves; each wave owns 8 timesteps (+1 overlap)
#define NBLK (T_TOTAL / TB)         // 6250
#define TPW 8                       // owned timesteps per wave
#define LPW (TPW + 1)               // loaded timesteps per wave (wave3's 9th = halo)

// Phase A: per-wave register tree-prefix. ALL 27 angle loads issued into
// register arrays, then sched_barrier(0) pins them (compiler may not sink
// loads to use sites) -> full-window MLP. 9 prefix chains per wave.
// Phase B: float4 loss/reg2/output pass. LDS ~20KB -> 8 blocks/CU.
__global__ __launch_bounds__(THREADS, 8) void bbf_fused(
    const float* __restrict__ lines,
    const float* __restrict__ rootsx,
    const float* __restrict__ rootsy,
    const float* __restrict__ rootsz,
    const float* __restrict__ ax,
    const float* __restrict__ ay,
    const float* __restrict__ az,
    const float* __restrict__ tarx,
    const float* __restrict__ tary,
    const float* __restrict__ w,
    float* __restrict__ outx,
    float* __restrict__ outy,
    float* __restrict__ outz,
    double* __restrict__ partials)   // [NBLK][2]: loss, reg2 per block
{
    __shared__ __align__(16) float xs[(TB + 1) * NP + 8];   // +8: phase-B overshoot
    __shared__ __align__(16) float ys[(TB + 1) * NP + 8];
    __shared__ __align__(16) float zs[(TB + 1) * NP + 8];
    __shared__ double redL[THREADS / 64], redR[THREADS / 64];

    const int tid  = threadIdx.x;
    const int lane = tid & 63;
    const int wv   = tid >> 6;
    const int t0   = blockIdx.x * TB;

    const bool isNode = (lane < NP);
    const bool isLimb = (lane >= 1 && lane < NP);
    const int  li     = isLimb ? (lane - 1) : 0;    // clamped limb index

    const float Lv = isLimb ? expf(lines[li % NB]) : 0.f;   // 0 masks non-limb lanes

    // ancestor jump table (pointer jumping: 1st, 2nd, 4th ancestor; root-clamped)
    const int a1 = isLimb ? ((lane - 1) >> 1) : 0;
    const int a2 = (a1 > 0) ? ((a1 - 1) >> 1) : 0;
    const int a3 = (a2 > 0) ? ((a2 - 1) >> 1) : 0;
    const int a4 = (a3 > 0) ? ((a3 - 1) >> 1) : 0;

    // ---- Phase A1: issue ALL 27 angle loads (9 timesteps x 3 comps) ----
    float xa[LPW], ya[LPW], za[LPW];
#pragma unroll
    for (int k = 0; k < LPW; ++k) {
        const int t = min(t0 + wv * TPW + k, T_TOTAL - 1);   // clamp last block
        const size_t gi = (size_t)t * NL + li;
        xa[k] = ax[gi];
        ya[k] = ay[gi];
        za[k] = az[gi];
    }
    __builtin_amdgcn_sched_barrier(0);   // loads may NOT sink past this point

    // ---- Phase A2: 8 (+1 for wave 3) independent prefix chains -> LDS ----
    const int kmax = (wv == 3 && t0 + TB < T_TOTAL) ? LPW : TPW;
#pragma unroll
    for (int k = 0; k < LPW; ++k) {
        if (k >= kmax) break;
        const int t_loc = wv * TPW + k;
        const int t = t0 + t_loc;
        const float x = xa[k], y = ya[k], z = za[k];
        const float n = sqrtf(x * x + y * y + z * z) + 1e-10f;
        const float s = Lv / n;                    // 0 for non-limb lanes
        float dx = x * s, dy = y * s, dz = z * s;
        dx += __shfl(dx, a1); dy += __shfl(dy, a1); dz += __shfl(dz, a1);
        dx += __shfl(dx, a2); dy += __shfl(dy, a2); dz += __shfl(dz, a2);
        dx += __shfl(dx, a4); dy += __shfl(dy, a4); dz += __shfl(dz, a4);
        if (isNode) {
            const int o = t_loc * NP + lane;
            xs[o] = dx + rootsx[t];                // t wave-uniform -> s_load
            ys[o] = dy + rootsy[t];
            zs[o] = dz + rootsz[t];
        }
    }
    __syncthreads();

    // ---- Phase B: float4 outputs + loss/reg2 ----
    const size_t gbase = (size_t)t0 * NP;          // blockIdx*1600 floats, 16B aligned
    const float4* tarx4 = (const float4*)(tarx + gbase);
    const float4* tary4 = (const float4*)(tary + gbase);
    const float4* w4    = (const float4*)(w + gbase);
    float4* outx4 = (float4*)(outx + gbase);
    float4* outy4 = (float4*)(outy + gbase);
    float4* outz4 = (float4*)(outz + gbase);

    float lossAcc = 0.f, regAcc = 0.f;
    for (int c = tid; c < (TB * NP) / 4; c += THREADS) {   // 400 float4 groups
        const int j = c << 2;
        const float4 X  = *(const float4*)&xs[j];
        const float4 Y  = *(const float4*)&ys[j];
        const float4 Z  = *(const float4*)&zs[j];
        outx4[c] = X;
        outy4[c] = Y;
        outz4[c] = Z;
        const float4 TX = tarx4[c];
        const float4 TY = tary4[c];
        const float4 WV = w4[c];
        // next-timestep values xs[j+50..j+53] via two aligned b128 reads
        const float4 XA = *(const float4*)&xs[j + 48];
        const float4 XB = *(const float4*)&xs[j + 52];
        const float4 YA = *(const float4*)&ys[j + 48];
        const float4 YB = *(const float4*)&ys[j + 52];
        const float4 ZA = *(const float4*)&zs[j + 48];
        const float4 ZB = *(const float4*)&zs[j + 52];
        const float xv[4] = {X.x, X.y, X.z, X.w};
        const float yv[4] = {Y.x, Y.y, Y.z, Y.w};
        const float zv[4] = {Z.x, Z.y, Z.z, Z.w};
        const float tx[4] = {TX.x, TX.y, TX.z, TX.w};
        const float ty[4] = {TY.x, TY.y, TY.z, TY.w};
        const float wvv[4] = {WV.x, WV.y, WV.z, WV.w};
        const float xn[4] = {XA.z, XA.w, XB.x, XB.y};
        const float yn[4] = {YA.z, YA.w, YB.x, YB.y};
        const float zn[4] = {ZA.z, ZA.w, ZB.x, ZB.y};
#pragma unroll
        for (int e = 0; e < 4; ++e) {
            const float dx = xv[e] - tx[e];
            const float dy = yv[e] - ty[e];
            lossAcc += wvv[e] * (dx * dx + dy * dy);
            const int t = t0 + (j + e) / NP;
            if (t < T_TOTAL - 1) {
                const float ddx = xv[e] - xn[e];
                const float ddy = yv[e] - yn[e];
                const float ddz = zv[e] - zn[e];
                regAcc += ddx * ddx + ddy * ddy + ddz * ddz;
            }
        }
    }

    // wave reduce -> cross-wave LDS -> per-block partial slot
    for (int off = 32; off > 0; off >>= 1) {
        lossAcc += __shfl_down(lossAcc, off);
        regAcc  += __shfl_down(regAcc, off);
    }
    if (lane == 0) { redL[wv] = (double)lossAcc; redR[wv] = (double)regAcc; }
    __syncthreads();
    if (tid == 0) {
        double l = 0.0, r = 0.0;
        for (int i = 0; i < THREADS / 64; ++i) { l += redL[i]; r += redR[i]; }
        partials[2 * (size_t)blockIdx.x]     = l;
        partials[2 * (size_t)blockIdx.x + 1] = r;
    }
}

__global__ __launch_bounds__(256) void bbf_finalize(
    const float* __restrict__ lines,
    const double* __restrict__ partials,
    float* __restrict__ out_total)
{
    __shared__ double rl[4], rr[4];
    const int tid = threadIdx.x;
    double l = 0.0, r = 0.0;
    for (int i = tid; i < NBLK; i += 256) {
        l += partials[2 * (size_t)i];
        r += partials[2 * (size_t)i + 1];
    }
    for (int off = 32; off > 0; off >>= 1) {
        l += __shfl_down(l, off);
        r += __shfl_down(r, off);
    }
    const int wid = tid >> 6;
    if ((tid & 63) == 0) { rl[wid] = l; rr[wid] = r; }
    __syncthreads();
    if (tid == 0) {
        double L = 0.0, R = 0.0;
        for (int i = 0; i < 4; ++i) { L += rl[i]; R += rr[i]; }
        double reg1 = 0.0;
        for (int i = 0; i < NB; ++i) reg1 += (double)expf(lines[i]);
        const double loss = L / ((double)T_TOTAL * (double)NP);
        const double reg2 = R / ((double)(T_TOTAL - 1) * (double)NP);
        *out_total = (float)(loss + 0.001 * reg1 + 0.1 * reg2);
    }
}

extern "C" void kernel_launch(void* const* d_in, const int* in_sizes, int n_in,
                              void* d_out, int out_size, void* d_ws, size_t ws_size,
                              hipStream_t stream) {
    const float* lines  = (const float*)d_in[0];
    const float* rootsx = (const float*)d_in[1];
    const float* rootsy = (const float*)d_in[2];
    const float* rootsz = (const float*)d_in[3];
    const float* ax     = (const float*)d_in[4];
    const float* ay     = (const float*)d_in[5];
    const float* az     = (const float*)d_in[6];
    const float* tarx   = (const float*)d_in[7];
    const float* tary   = (const float*)d_in[8];
    const float* w      = (const float*)d_in[9];

    float* out = (float*)d_out;
    const size_t plane = (size_t)T_TOTAL * NP;
    float* outx = out;
    float* outy = out + plane;
    float* outz = out + 2 * plane;
    float* out_total = out + 3 * plane;

    double* partials = (double*)d_ws;   // NBLK*2 doubles = 100 KB

    bbf_fused<<<NBLK, THREADS, 0, stream>>>(
        lines, rootsx, rootsy, rootsz, ax, ay, az, tarx, tary, w,
        outx, outy, outz, partials);
    bbf_finalize<<<1, 256, 0, stream>>>(lines, partials, out_total);
}

// Round 11
// 81.483 us; speedup vs baseline: 1.3562x; 1.3562x over previous
//
#include <hip/hip_runtime.h>

#define T_TOTAL 200000
#define NL 49
#define NP 50
#define NB 20
#define TB 32                       // timesteps per block; 200000 % 32 == 0
#define THREADS 256                 // 4 waves; each wave owns 8 timesteps (+1 overlap)
#define NBLK (T_TOTAL / TB)         // 6250
#define TPW 8                       // owned timesteps per wave
#define LPW (TPW + 1)               // loaded timesteps per wave (wave3's 9th = halo)

// Phase A: per-wave register tree-prefix. ALL 27 angle loads issued into
// register arrays, then sched_barrier(0) pins them -> full-window MLP.
// __launch_bounds__(,6) gives the allocator ~85 VGPRs so the staged loads
// stay in registers (R10's (,8)->64 cap spilled them to scratch: WRITE 230MB).
// Phase B: float4 loss/reg2/output pass. LDS ~20KB.
__global__ __launch_bounds__(THREADS, 6) void bbf_fused(
    const float* __restrict__ lines,
    const float* __restrict__ rootsx,
    const float* __restrict__ rootsy,
    const float* __restrict__ rootsz,
    const float* __restrict__ ax,
    const float* __restrict__ ay,
    const float* __restrict__ az,
    const float* __restrict__ tarx,
    const float* __restrict__ tary,
    const float* __restrict__ w,
    float* __restrict__ outx,
    float* __restrict__ outy,
    float* __restrict__ outz,
    double* __restrict__ partials)   // [NBLK][2]: loss, reg2 per block
{
    __shared__ __align__(16) float xs[(TB + 1) * NP + 8];   // +8: phase-B overshoot
    __shared__ __align__(16) float ys[(TB + 1) * NP + 8];
    __shared__ __align__(16) float zs[(TB + 1) * NP + 8];
    __shared__ double redL[THREADS / 64], redR[THREADS / 64];

    const int tid  = threadIdx.x;
    const int lane = tid & 63;
    const int wv   = tid >> 6;
    const int t0   = blockIdx.x * TB;

    const bool isNode = (lane < NP);
    const bool isLimb = (lane >= 1 && lane < NP);
    const int  li     = isLimb ? (lane - 1) : 0;    // clamped limb index

    const float Lv = isLimb ? expf(lines[li % NB]) : 0.f;   // 0 masks non-limb lanes

    // ancestor jump table (pointer jumping: 1st, 2nd, 4th ancestor; root-clamped)
    const int a1 = isLimb ? ((lane - 1) >> 1) : 0;
    const int a2 = (a1 > 0) ? ((a1 - 1) >> 1) : 0;
    const int a3 = (a2 > 0) ? ((a2 - 1) >> 1) : 0;
    const int a4 = (a3 > 0) ? ((a3 - 1) >> 1) : 0;

    // ---- Phase A1: issue ALL 27 angle loads (9 timesteps x 3 comps) ----
    float xa[LPW], ya[LPW], za[LPW];
#pragma unroll
    for (int k = 0; k < LPW; ++k) {
        const int t = min(t0 + wv * TPW + k, T_TOTAL - 1);   // clamp last block
        const size_t gi = (size_t)t * NL + li;
        xa[k] = ax[gi];
        ya[k] = ay[gi];
        za[k] = za != nullptr ? az[gi] : 0.f;   // (az load; keep simple form)
    }
    __builtin_amdgcn_sched_barrier(0);   // loads may NOT sink past this point

    // ---- Phase A2: 8 (+1 for wave 3) independent prefix chains -> LDS ----
    const int kmax = (wv == 3 && t0 + TB < T_TOTAL) ? LPW : TPW;
#pragma unroll
    for (int k = 0; k < LPW; ++k) {
        if (k < kmax) {
            const int t_loc = wv * TPW + k;
            const int t = t0 + t_loc;
            const float x = xa[k], y = ya[k], z = za[k];
            const float n = sqrtf(x * x + y * y + z * z) + 1e-10f;
            const float s = Lv / n;                    // 0 for non-limb lanes
            float dx = x * s, dy = y * s, dz = z * s;
            dx += __shfl(dx, a1); dy += __shfl(dy, a1); dz += __shfl(dz, a1);
            dx += __shfl(dx, a2); dy += __shfl(dy, a2); dz += __shfl(dz, a2);
            dx += __shfl(dx, a4); dy += __shfl(dy, a4); dz += __shfl(dz, a4);
            if (isNode) {
                const int o = t_loc * NP + lane;
                xs[o] = dx + rootsx[t];                // t wave-uniform -> s_load
                ys[o] = dy + rootsy[t];
                zs[o] = dz + rootsz[t];
            }
        }
    }
    __syncthreads();

    // ---- Phase B: float4 outputs + loss/reg2 ----
    const size_t gbase = (size_t)t0 * NP;          // blockIdx*1600 floats, 16B aligned
    const float4* tarx4 = (const float4*)(tarx + gbase);
    const float4* tary4 = (const float4*)(tary + gbase);
    const float4* w4    = (const float4*)(w + gbase);
    float4* outx4 = (float4*)(outx + gbase);
    float4* outy4 = (float4*)(outy + gbase);
    float4* outz4 = (float4*)(outz + gbase);

    float lossAcc = 0.f, regAcc = 0.f;
    for (int c = tid; c < (TB * NP) / 4; c += THREADS) {   // 400 float4 groups
        const int j = c << 2;
        const float4 X  = *(const float4*)&xs[j];
        const float4 Y  = *(const float4*)&ys[j];
        const float4 Z  = *(const float4*)&zs[j];
        outx4[c] = X;
        outy4[c] = Y;
        outz4[c] = Z;
        const float4 TX = tarx4[c];
        const float4 TY = tary4[c];
        const float4 WV = w4[c];
        // next-timestep values xs[j+50..j+53] via two aligned b128 reads
        const float4 XA = *(const float4*)&xs[j + 48];
        const float4 XB = *(const float4*)&xs[j + 52];
        const float4 YA = *(const float4*)&ys[j + 48];
        const float4 YB = *(const float4*)&ys[j + 52];
        const float4 ZA = *(const float4*)&zs[j + 48];
        const float4 ZB = *(const float4*)&zs[j + 52];
        const float xv[4] = {X.x, X.y, X.z, X.w};
        const float yv[4] = {Y.x, Y.y, Y.z, Y.w};
        const float zv[4] = {Z.x, Z.y, Z.z, Z.w};
        const float tx[4] = {TX.x, TX.y, TX.z, TX.w};
        const float ty[4] = {TY.x, TY.y, TY.z, TY.w};
        const float wvv[4] = {WV.x, WV.y, WV.z, WV.w};
        const float xn[4] = {XA.z, XA.w, XB.x, XB.y};
        const float yn[4] = {YA.z, YA.w, YB.x, YB.y};
        const float zn[4] = {ZA.z, ZA.w, ZB.x, ZB.y};
#pragma unroll
        for (int e = 0; e < 4; ++e) {
            const float dx = xv[e] - tx[e];
            const float dy = yv[e] - ty[e];
            lossAcc += wvv[e] * (dx * dx + dy * dy);
            const int t = t0 + (j + e) / NP;
            if (t < T_TOTAL - 1) {
                const float ddx = xv[e] - xn[e];
                const float ddy = yv[e] - yn[e];
                const float ddz = zv[e] - zn[e];
                regAcc += ddx * ddx + ddy * ddy + ddz * ddz;
            }
        }
    }

    // wave reduce -> cross-wave LDS -> per-block partial slot
    for (int off = 32; off > 0; off >>= 1) {
        lossAcc += __shfl_down(lossAcc, off);
        regAcc  += __shfl_down(regAcc, off);
    }
    if (lane == 0) { redL[wv] = (double)lossAcc; redR[wv] = (double)regAcc; }
    __syncthreads();
    if (tid == 0) {
        double l = 0.0, r = 0.0;
        for (int i = 0; i < THREADS / 64; ++i) { l += redL[i]; r += redR[i]; }
        partials[2 * (size_t)blockIdx.x]     = l;
        partials[2 * (size_t)blockIdx.x + 1] = r;
    }
}

__global__ __launch_bounds__(256) void bbf_finalize(
    const float* __restrict__ lines,
    const double* __restrict__ partials,
    float* __restrict__ out_total)
{
    __shared__ double rl[4], rr[4];
    const int tid = threadIdx.x;
    double l = 0.0, r = 0.0;
    for (int i = tid; i < NBLK; i += 256) {
        l += partials[2 * (size_t)i];
        r += partials[2 * (size_t)i + 1];
    }
    for (int off = 32; off > 0; off >>= 1) {
        l += __shfl_down(l, off);
        r += __shfl_down(r, off);
    }
    const int wid = tid >> 6;
    if ((tid & 63) == 0) { rl[wid] = l; rr[wid] = r; }
    __syncthreads();
    if (tid == 0) {
        double L = 0.0, R = 0.0;
        for (int i = 0; i < 4; ++i) { L += rl[i]; R += rr[i]; }
        double reg1 = 0.0;
        for (int i = 0; i < NB; ++i) reg1 += (double)expf(lines[i]);
        const double loss = L / ((double)T_TOTAL * (double)NP);
        const double reg2 = R / ((double)(T_TOTAL - 1) * (double)NP);
        *out_total = (float)(loss + 0.001 * reg1 + 0.1 * reg2);
    }
}

extern "C" void kernel_launch(void* const* d_in, const int* in_sizes, int n_in,
                              void* d_out, int out_size, void* d_ws, size_t ws_size,
                              hipStream_t stream) {
    const float* lines  = (const float*)d_in[0];
    const float* rootsx = (const float*)d_in[1];
    const float* rootsy = (const float*)d_in[2];
    const float* rootsz = (const float*)d_in[3];
    const float* ax     = (const float*)d_in[4];
    const float* ay     = (const float*)d_in[5];
    const float* az     = (const float*)d_in[6];
    const float* tarx   = (const float*)d_in[7];
    const float* tary   = (const float*)d_in[8];
    const float* w      = (const float*)d_in[9];

    float* out = (float*)d_out;
    const size_t plane = (size_t)T_TOTAL * NP;
    float* outx = out;
    float* outy = out + plane;
    float* outz = out + 2 * plane;
    float* out_total = out + 3 * plane;

    double* partials = (double*)d_ws;   // NBLK*2 doubles = 100 KB

    bbf_fused<<<NBLK, THREADS, 0, stream>>>(
        lines, rootsx, rootsy, rootsz, ax, ay, az, tarx, tary, w,
        outx, outy, outz, partials);
    bbf_finalize<<<1, 256, 0, stream>>>(lines, partials, out_total);
}